// Round 12
// baseline (700.612 us; speedup 1.0000x reference)
//
#include <hip/hip_runtime.h>

#define DIN 768
#define DL  12288
#define CAP 320
#define CAP2 512
#define BCAP 2048
#define TCAND 2.9f
#define MARGIN 0.03f
#define UB 0.015f
#define UMAX 64
#define KMAX 128

typedef __attribute__((ext_vector_type(8))) _Float16 half8;
typedef __attribute__((ext_vector_type(4))) _Float16 half4v;
typedef __attribute__((ext_vector_type(4))) float f32x4;

__device__ __forceinline__ void gl_lds16(const void* g, void* s) {
  __builtin_amdgcn_global_load_lds(
      (const __attribute__((address_space(1))) unsigned int*)g,
      (__attribute__((address_space(3))) unsigned int*)s, 16, 0, 0);
}
__device__ __forceinline__ void wait_lgkm0_fence() {
  asm volatile("s_waitcnt lgkmcnt(0)" ::: "memory");
  __builtin_amdgcn_sched_barrier(0);   // rule #18
}
__device__ __forceinline__ void wait_vm0() {
  asm volatile("s_waitcnt vmcnt(0)" ::: "memory");
}

// ------- merged prep: split_x | split_w | transpose | cnt/flag zero (block-range) -------
#define NBX (8192 * DIN / 1024)          // 6144
#define NBW (DL * DIN / 1024)            // 9216
#define NBT ((DL / 32) * (DIN / 32))     // 9216

template <int ZMETA>
__global__ __launch_bounds__(256) void k_prep(
    const float* __restrict__ x, const float* __restrict__ b_pre,
    const float* __restrict__ W_enc, const float* __restrict__ W_dec,
    _Float16* __restrict__ Ah, _Float16* __restrict__ Bh, _Float16* __restrict__ WT,
    int* __restrict__ meta)   // cnt(8192) + flag(8192)
{
  const int b = blockIdx.x, tid = threadIdx.x;
  if (b < NBX) {
    const int i4 = b * 256 + tid;
    const int col4 = (i4 % (DIN / 4)) * 4;
    const float4 xv = *(const float4*)&x[(size_t)i4 * 4];
    const float4 bp = *(const float4*)&b_pre[col4];
    half4v o;
    o.x = (_Float16)(xv.x - bp.x);
    o.y = (_Float16)(xv.y - bp.y);
    o.z = (_Float16)(xv.z - bp.z);
    o.w = (_Float16)(xv.w - bp.w);
    *(half4v*)&Ah[(size_t)i4 * 4] = o;
  } else if (b < NBX + NBW) {
    const int i4 = (b - NBX) * 256 + tid;
    const float4 wv = *(const float4*)&W_enc[(size_t)i4 * 4];
    half4v o;
    o.x = (_Float16)wv.x; o.y = (_Float16)wv.y;
    o.z = (_Float16)wv.z; o.w = (_Float16)wv.w;
    *(half4v*)&Bh[(size_t)i4 * 4] = o;
  } else if (b < NBX + NBW + NBT) {
    const int idx = b - NBX - NBW;
    const int c0 = (idx % (DL / 32)) * 32;
    const int r0 = (idx / (DL / 32)) * 32;
    const int xx = tid & 31, yy = tid >> 5;
    __shared__ float t[32][33];
#pragma unroll
    for (int dy = 0; dy < 32; dy += 8)
      t[yy + dy][xx] = W_dec[(size_t)(r0 + yy + dy) * DL + c0 + xx];
    __syncthreads();
#pragma unroll
    for (int dy = 0; dy < 32; dy += 8)
      WT[(size_t)(c0 + yy + dy) * DIN + r0 + xx] = (_Float16)t[xx][yy + dy];
  } else if (ZMETA) {
    const int4 z4 = {0, 0, 0, 0};   // 16384 ints = 4096 int4; 256 thr x 16
#pragma unroll
    for (int s = 0; s < 16; ++s) ((int4*)meta)[tid * 16 + s] = z4;
  }
}

// ------- fp16 MFMA encode; EMIT=1: z-tile zero in prologue + block-batched candidates -----
#define BM 256
#define BN 256
#define BKE 64
#define NKT (DIN / BKE)   // 12

template <int EMIT>
__global__ __launch_bounds__(512) void k_encode_f16(
    const _Float16* __restrict__ Ah, const _Float16* __restrict__ Bh,
    const float* __restrict__ b_enc, float* __restrict__ aout,
    int* __restrict__ cnt, int2* __restrict__ cand, float* __restrict__ zout)
{
  __shared__ _Float16 sA[2][BM][BKE];
  __shared__ _Float16 sB[2][BN][BKE];
  __shared__ int s_bcnt;
  const int tid = threadIdx.x, wave = tid >> 6, lane = tid & 63;
  const int wm = wave >> 2, wn = wave & 3;
  const int fr = lane & 15, fc = lane >> 4;

  const int q = ((8192 / BM) * (DL / BN)) >> 3;
  const int wg = (blockIdx.x & 7) * q + (blockIdx.x >> 3);
  const int bm = (wg / (DL / BN)) * BM;
  const int bn = (wg % (DL / BN)) * BN;

  const int lrow = lane >> 3;
  const int lcol = ((lane & 7) ^ lrow) << 3;
  const _Float16* gA = Ah + (size_t)(bm + lrow) * DIN + lcol;
  const _Float16* gB = Bh + (size_t)(bn + lrow) * DIN + lcol;

  f32x4 acc[8][4];
#pragma unroll
  for (int i = 0; i < 8; ++i)
#pragma unroll
    for (int j = 0; j < 4; ++j) acc[i][j] = f32x4{0.f, 0.f, 0.f, 0.f};

#define STAGE_TILE(buf, tt)                                                      \
  {                                                                              \
    _Pragma("unroll")                                                            \
    for (int s4 = 0; s4 < 4; ++s4) {                                             \
      const int s8 = (wave + s4 * 8) * 8;                                        \
      gl_lds16(gA + (size_t)s8 * DIN + (tt) * BKE, &sA[buf][s8][0]);             \
      gl_lds16(gB + (size_t)s8 * DIN + (tt) * BKE, &sB[buf][s8][0]);             \
    }                                                                            \
  }

#define LOADQ(p, mh, nh)                                                         \
  {                                                                              \
    const char* bA = (const char*)&sA[p][0][0];                                  \
    const char* bB = (const char*)&sB[p][0][0];                                  \
    _Pragma("unroll")                                                            \
    for (int i = 0; i < 4; ++i)                                                  \
      _Pragma("unroll")                                                          \
      for (int ks = 0; ks < 2; ++ks) {                                           \
        const int row = wm * 128 + ((mh) * 4 + i) * 16 + fr;                     \
        const int ph = (ks * 4 + fc) ^ (fr & 7);                                 \
        af[i][ks] = *(const half8*)(bA + row * (BKE * 2) + ph * 16);             \
      }                                                                          \
    _Pragma("unroll")                                                            \
    for (int j = 0; j < 2; ++j)                                                  \
      _Pragma("unroll")                                                          \
      for (int ks = 0; ks < 2; ++ks) {                                           \
        const int row = wn * 64 + ((nh) * 2 + j) * 16 + fr;                      \
        const int ph = (ks * 4 + fc) ^ (fr & 7);                                 \
        bf[j][ks] = *(const half8*)(bB + row * (BKE * 2) + ph * 16);             \
      }                                                                          \
  }

#define MFMAQ(mh, nh)                                                            \
  __builtin_amdgcn_s_setprio(1);                                                 \
  _Pragma("unroll")                                                              \
  for (int i = 0; i < 4; ++i)                                                    \
    _Pragma("unroll")                                                            \
    for (int j = 0; j < 2; ++j)                                                  \
      _Pragma("unroll")                                                          \
      for (int ks = 0; ks < 2; ++ks)                                             \
        acc[(mh) * 4 + i][(nh) * 2 + j] = __builtin_amdgcn_mfma_f32_16x16x32_f16( \
            af[i][ks], bf[j][ks], acc[(mh) * 4 + i][(nh) * 2 + j], 0, 0, 0);     \
  __builtin_amdgcn_s_setprio(0);

  half8 af[4][2], bf[2][2];

  // prologue: stage loads FIRST (oldest), then z-tile zero stores; counted wait
  // drains exactly the 8 stage loads (vmcnt in-order retire) -> stores overlap K-loop
  STAGE_TILE(0, 0)
  if (EMIT) {
    const float4 zz4 = {0.f, 0.f, 0.f, 0.f};
#pragma unroll
    for (int s = 0; s < 32; ++s)   // 8 waves x 1 row-segment each per iter; 32 iters = 256 rows
      *(float4*)&zout[(size_t)(bm + s * 8 + wave) * DL + bn + lane * 4] = zz4;
    asm volatile("s_waitcnt vmcnt(32)" ::: "memory");
  } else {
    wait_vm0();
  }
  __builtin_amdgcn_s_barrier();

#pragma unroll 1
  for (int t = 0; t < NKT; ++t) {
    const int p = t & 1;
    LOADQ(p, 0, 0)
    if (t + 1 < NKT) STAGE_TILE(p ^ 1, t + 1)
    __builtin_amdgcn_s_barrier();
    wait_lgkm0_fence();
    MFMAQ(0, 0)
    __builtin_amdgcn_s_barrier();
    LOADQ(p, 0, 1)
    __builtin_amdgcn_s_barrier();
    wait_lgkm0_fence();
    MFMAQ(0, 1)
    __builtin_amdgcn_s_barrier();
    LOADQ(p, 1, 0)
    __builtin_amdgcn_s_barrier();
    wait_lgkm0_fence();
    MFMAQ(1, 0)
    __builtin_amdgcn_s_barrier();
    LOADQ(p, 1, 1)
    wait_vm0();
    __builtin_amdgcn_s_barrier();
    wait_lgkm0_fence();
    MFMAQ(1, 1)
    __builtin_amdgcn_s_barrier();
  }

  // K-loop LDS done; reuse sA/sB as candidate scratch
  unsigned* pk   = (unsigned*)&sA[0][0][0];   // BCAP packed (lrow<<8|lcol)
  float*    pv   = (float*)&sA[1][0][0];      // BCAP values
  int*      lcnt = (int*)&sB[0][0][0];        // 256 per-local-row counts -> cursors
  if (EMIT) {
    if (tid == 0) s_bcnt = 0;
    if (tid < 256) lcnt[tid] = 0;
    __syncthreads();
  }

#pragma unroll
  for (int j = 0; j < 4; ++j) {
    const int col = bn + wn * 64 + j * 16 + fr;
    const float be = b_enc[col];
#pragma unroll
    for (int i = 0; i < 8; ++i) {
      const int row0 = bm + wm * 128 + i * 16 + fc * 4;
#pragma unroll
      for (int r = 0; r < 4; ++r) {
        const float v = acc[i][j][r] + be;
        aout[(size_t)(row0 + r) * DL + col] = v;
        if (EMIT && v > TCAND) {           // LDS-only compaction (no vmcnt stalls)
          const int lr = wm * 128 + i * 16 + fc * 4 + r;
          const int lc = wn * 64 + j * 16 + fr;
          const int p2 = atomicAdd(&s_bcnt, 1);
          if (p2 < BCAP) {
            pk[p2] = ((unsigned)lr << 8) | (unsigned)lc;
            pv[p2] = v;
          }
          atomicAdd(&lcnt[lr], 1);
        }
      }
    }
  }

  if (EMIT) {
    __syncthreads();
    const int total = s_bcnt;
    if (total > BCAP) {
      // overflow (P~0): poison rows -> k_fast flags -> k_full redoes them
      if (tid < 256) atomicAdd(&cnt[bm + tid], CAP2);
    } else {
      if (tid < 256) {                     // one global reservation per row per block
        const int c = lcnt[tid];
        lcnt[tid] = c ? atomicAdd(&cnt[bm + tid], c) : 0;
      }
      __syncthreads();
      for (int e = tid; e < total; e += 512) {
        const unsigned pkv = pk[e];
        const int lr = pkv >> 8, lc = pkv & 255u;
        const int p2 = atomicAdd(&lcnt[lr], 1);
        if (p2 < CAP2) {
          int2 o; o.x = __float_as_int(pv[e]); o.y = bn + lc;
          cand[(size_t)(bm + lr) * CAP2 + p2] = o;
        }
      }
    }
  }
#undef STAGE_TILE
#undef LOADQ
#undef MFMAQ
}

// ====== FAST back end: candidates from encode; z pre-zeroed; scatter + decode =============
__global__ __launch_bounds__(512) void k_fast(
    const int* __restrict__ cnt, const int2* __restrict__ cand,
    const float* __restrict__ x, const float* __restrict__ b_pre,
    const float* __restrict__ W, const float* __restrict__ b_enc,
    const int* __restrict__ kp, const _Float16* __restrict__ WT,
    const float* __restrict__ b_dec, float* __restrict__ z,
    float* __restrict__ xhat, int* __restrict__ flag)
{
  const int row = blockIdx.x, tid = threadIdx.x;
  const int wave = tid >> 6, lane = tid & 63;
  const int kk = min(max(kp[0], 1), KMAX);
  float* zr = z + (size_t)row * DL;

  __shared__ float cv[CAP2];
  __shared__ int ci[CAP2];
  __shared__ double x0[DIN];
  __shared__ float s_ak;
  __shared__ int s_nw, s_ucnt;
  __shared__ int uidx[UMAX];
  __shared__ double uex[UMAX];
  __shared__ int widx[KMAX];
  __shared__ float wval[KMAX];

  const int Craw = cnt[row];
  const int C = min(Craw, CAP2);
  for (int i = tid; i < C; i += 512) {
    const int2 p = cand[(size_t)row * CAP2 + i];
    cv[i] = __int_as_float(p.x);
    ci[i] = p.y;
  }
  for (int i = tid; i < DIN; i += 512)
    x0[i] = (double)x[(size_t)row * DIN + i] - (double)b_pre[i];
  if (tid == 0) { s_ak = -1e30f; s_nw = 0; s_ucnt = 0; }
  __syncthreads();

  bool defic = (Craw >= CAP2) || (C < kk);   // uniform
  if (!defic) {
    if (tid < C) {
      const float mv = cv[tid];
      const int mi = ci[tid];
      int r = 0;
      for (int j = 0; j < C; ++j) {
        const float fj = cv[j];
        if (fj > mv || (fj == mv && ci[j] < mi)) ++r;
      }
      if (r == kk - 1) s_ak = mv;
    }
    __syncthreads();
    if (s_ak - UB <= TCAND) defic = true;    // excluded (<=TCAND) values could reach band
  } else {
    __syncthreads();
  }
  if (defic) {
    if (tid == 0) flag[row] = 1;
    return;
  }
  const float ak = s_ak;

  if (tid < C) {
    const float mv = cv[tid];
    if (mv > ak + UB) {
      const int p = atomicAdd(&s_nw, 1);
      widx[p] = ci[tid]; wval[p] = mv;
    } else if (mv >= ak - UB) {
      const int p = atomicAdd(&s_ucnt, 1);
      if (p < UMAX) uidx[p] = ci[tid];
    }
  }
  __syncthreads();
  const int nci = s_nw;
  const int ucnt = min(s_ucnt, UMAX);

  for (int c = wave; c < ucnt; c += 8) {
    const int idx = uidx[c];
    const float* wrow = W + (size_t)idx * DIN;
    double s = 0.0;
#pragma unroll
    for (int it = 0; it < DIN / 64; ++it)
      s = fma(x0[lane + it * 64], (double)wrow[lane + it * 64], s);
#pragma unroll
    for (int mm = 32; mm; mm >>= 1) s += __shfl_xor(s, mm);
    if (lane == 0) {
      const double e = s + (double)b_enc[idx];
      uex[c] = e > 0.0 ? e : 0.0;
    }
  }
  __syncthreads();

  const int utake = min(kk - nci, ucnt);
  if (tid < ucnt) {
    const double mv = uex[tid];
    const int mi = uidx[tid];
    int r = 0;
    for (int j = 0; j < ucnt; ++j) {
      const double fj = uex[j];
      if (fj > mv || (fj == mv && uidx[j] < mi)) ++r;
    }
    if (r < utake) {
      const int p = atomicAdd(&s_nw, 1);
      widx[p] = mi; wval[p] = (float)mv;
    }
  }
  __syncthreads();
  const int nW = s_nw;

  if (tid < nW) zr[widx[tid]] = wval[tid];

  if (tid < 192) {
    float4 acc = ((const float4*)b_dec)[tid];
    for (int j = 0; j < nW; ++j) {
      const float vv = wval[j];
      const half4v w4 = *(const half4v*)(WT + (size_t)widx[j] * DIN + tid * 4);
      acc.x = fmaf(vv, (float)w4.x, acc.x);
      acc.y = fmaf(vv, (float)w4.y, acc.y);
      acc.z = fmaf(vv, (float)w4.z, acc.z);
      acc.w = fmaf(vv, (float)w4.w, acc.w);
    }
    ((float4*)(xhat + (size_t)row * DIN))[tid] = acc;
  }
}

// ====== FULL row back end (fallback for flagged rows; FORCE_ALL=1 for small-ws path) ======
template <int FORCE_ALL, int ZERO_Z>
__global__ __launch_bounds__(512) void k_full(
    const float* __restrict__ a, const float* __restrict__ x,
    const float* __restrict__ b_pre, const float* __restrict__ W,
    const float* __restrict__ b_enc, const int* __restrict__ kp,
    const _Float16* __restrict__ WT, const float* __restrict__ b_dec,
    float* __restrict__ z, float* __restrict__ xhat, const int* __restrict__ flag)
{
  const int row = blockIdx.x, tid = threadIdx.x;
  if (!FORCE_ALL && flag[row] == 0) return;
  const int wave = tid >> 6, lane = tid & 63;
  const int kk = min(max(kp[0], 1), KMAX);
  const float* ar = a + (size_t)row * DL;
  float* zr = z + (size_t)row * DL;

  __shared__ unsigned hist[4][512];
  __shared__ float s_wmax[8];
  __shared__ unsigned s_wsuf[8];
  __shared__ float s_Tm;
  __shared__ int s_cnt;
  __shared__ int cidx[CAP];
  __shared__ float caf[CAP];
  __shared__ double x0[DIN];
  __shared__ float s_ak;
  __shared__ int s_ucnt, s_nw;
  __shared__ int uidx[UMAX];
  __shared__ double uex[UMAX];
  __shared__ int widx[KMAX];
  __shared__ float wval[KMAX];

  float4 v[6];
#pragma unroll
  for (int j = 0; j < 6; ++j) {
    float4 t4 = ((const float4*)ar)[tid + 512 * j];
    t4.x = fmaxf(t4.x, 0.f); t4.y = fmaxf(t4.y, 0.f);
    t4.z = fmaxf(t4.z, 0.f); t4.w = fmaxf(t4.w, 0.f);
    v[j] = t4;
    if (ZERO_Z) {
      const float4 zz = {0.f, 0.f, 0.f, 0.f};
      ((float4*)zr)[tid + 512 * j] = zz;
    }
  }
  for (int i = tid; i < DIN; i += 512)
    x0[i] = (double)x[(size_t)row * DIN + i] - (double)b_pre[i];
  float m = 0.f;
#pragma unroll
  for (int j = 0; j < 6; ++j)
    m = fmaxf(m, fmaxf(fmaxf(v[j].x, v[j].y), fmaxf(v[j].z, v[j].w)));
#pragma unroll
  for (int off = 32; off; off >>= 1) m = fmaxf(m, __shfl_xor(m, off));
  if (lane == 0) s_wmax[wave] = m;
  if (tid == 0) { s_cnt = 0; s_Tm = -1.f; s_ak = -1e30f; s_ucnt = 0; s_nw = 0; }
  __syncthreads();
  float rmax = s_wmax[0];
#pragma unroll
  for (int w2 = 1; w2 < 8; ++w2) rmax = fmaxf(rmax, s_wmax[w2]);

  float Tm;
  if (rmax <= 0.f) {
    Tm = 1e30f;
  } else {
    const float scale = 512.f / rmax;
    unsigned need = (unsigned)kk;
    bool found = false;
    for (int phase = 0; phase < 2 && !found; ++phase) {
      for (int i = tid; i < 4 * 512; i += 512) (&hist[0][0])[i] = 0u;
      __syncthreads();
      unsigned* h = hist[wave & 3];
      const float sc = (phase == 0) ? scale : scale * 8.f;
#pragma unroll
      for (int j = 0; j < 6; ++j) {
        const float vv[4] = {v[j].x, v[j].y, v[j].z, v[j].w};
#pragma unroll
        for (int e = 0; e < 4; ++e) {
          const float val = vv[e];
          if (val > 0.f) {
            const float fb = val * scale;
            if (phase == 0) {
              if (fb >= 64.f) atomicAdd(&h[min(511, (int)fb)], 1u);
            } else {
              if (fb < 64.f) atomicAdd(&h[min(511, (int)(val * sc))], 1u);
            }
          }
        }
      }
      __syncthreads();
      const unsigned st = hist[0][tid] + hist[1][tid] + hist[2][tid] + hist[3][tid];
      unsigned s = st;
#pragma unroll
      for (int off = 1; off < 64; off <<= 1) {
        const unsigned o = __shfl_down(s, off);
        if (lane + off < 64) s += o;
      }
      if (lane == 0) s_wsuf[wave] = s;
      __syncthreads();
      unsigned above_w = 0, total = 0;
#pragma unroll
      for (int w2 = 0; w2 < 8; ++w2) {
        total += s_wsuf[w2];
        if (w2 > wave) above_w += s_wsuf[w2];
      }
      const unsigned inc = s + above_w;
      const unsigned excl = inc - st;
      if (total >= need) {
        if (inc >= need && excl < need)
          s_Tm = (float)tid / sc - MARGIN;
        found = true;
      } else {
        need -= total;
      }
      __syncthreads();
    }
    Tm = s_Tm;
  }

#pragma unroll
  for (int j = 0; j < 6; ++j) {
    const float vv[4] = {v[j].x, v[j].y, v[j].z, v[j].w};
#pragma unroll
    for (int e = 0; e < 4; ++e) {
      if (vv[e] > 0.f && vv[e] >= Tm) {
        const int p = atomicAdd(&s_cnt, 1);
        if (p < CAP) { cidx[p] = (tid + 512 * j) * 4 + e; caf[p] = vv[e]; }
      }
    }
  }
  __syncthreads();
  const int C = min(s_cnt, CAP);

  if (C > kk) {
    if (tid < C) {
      const float mv = caf[tid];
      const int mi = cidx[tid];
      int r = 0;
      for (int j = 0; j < C; ++j) {
        const float fj = caf[j];
        if (fj > mv || (fj == mv && cidx[j] < mi)) ++r;
      }
      if (r == kk - 1) s_ak = mv;
    }
    __syncthreads();
  }
  const float ak = s_ak;

  if (tid < C) {
    const float mv = caf[tid];
    if (C <= kk || mv > ak + UB) {
      const int p = atomicAdd(&s_nw, 1);
      widx[p] = cidx[tid]; wval[p] = mv;
    } else if (mv >= ak - UB) {
      const int p = atomicAdd(&s_ucnt, 1);
      if (p < UMAX) uidx[p] = cidx[tid];
    }
  }
  __syncthreads();
  const int nci = s_nw;
  const int ucnt = min(s_ucnt, UMAX);

  for (int c = wave; c < ucnt; c += 8) {
    const int idx = uidx[c];
    const float* wrow = W + (size_t)idx * DIN;
    double s = 0.0;
#pragma unroll
    for (int it = 0; it < DIN / 64; ++it)
      s = fma(x0[lane + it * 64], (double)wrow[lane + it * 64], s);
#pragma unroll
    for (int mm = 32; mm; mm >>= 1) s += __shfl_xor(s, mm);
    if (lane == 0) {
      const double e = s + (double)b_enc[idx];
      uex[c] = e > 0.0 ? e : 0.0;
    }
  }
  __syncthreads();

  const int utake = min(kk - nci, ucnt);
  if (tid < ucnt) {
    const double mv = uex[tid];
    const int mi = uidx[tid];
    int r = 0;
    for (int j = 0; j < ucnt; ++j) {
      const double fj = uex[j];
      if (fj > mv || (fj == mv && uidx[j] < mi)) ++r;
    }
    if (r < utake) {
      const int p = atomicAdd(&s_nw, 1);
      widx[p] = mi; wval[p] = (float)mv;
    }
  }
  __syncthreads();
  const int nW = s_nw;

  if (tid < nW) zr[widx[tid]] = wval[tid];

  if (tid < 192) {
    float4 acc = ((const float4*)b_dec)[tid];
    for (int j = 0; j < nW; ++j) {
      const float vv = wval[j];
      const half4v w4 = *(const half4v*)(WT + (size_t)widx[j] * DIN + tid * 4);
      acc.x = fmaf(vv, (float)w4.x, acc.x);
      acc.y = fmaf(vv, (float)w4.y, acc.y);
      acc.z = fmaf(vv, (float)w4.z, acc.z);
      acc.w = fmaf(vv, (float)w4.w, acc.w);
    }
    ((float4*)(xhat + (size_t)row * DIN))[tid] = acc;
  }
}

extern "C" void kernel_launch(void* const* d_in, const int* in_sizes, int n_in,
                              void* d_out, int out_size, void* d_ws, size_t ws_size,
                              hipStream_t stream)
{
  const float* x     = (const float*)d_in[0];
  const float* b_pre = (const float*)d_in[1];
  const float* W_enc = (const float*)d_in[2];
  const float* b_enc = (const float*)d_in[3];
  const float* W_dec = (const float*)d_in[4];
  const float* b_dec = (const float*)d_in[5];
  const int*   kp    = (const int*)d_in[6];
  const int M = in_sizes[0] / DIN;   // 8192

  float* xhat = (float*)d_out;
  float* z    = xhat + (size_t)M * DIN;
  float* a    = z + (size_t)M * DL;

  const bool bigws = ws_size >= ((size_t)192 << 20);

  if (bigws) {   // d_ws: [0,64K) cnt+flag | [1M,34.6M) cand | [40M) WT16 | [64M) Ah | [96M) Bh
    int*      cnt  = (int*)d_ws;
    int*      flag = (int*)d_ws + M;
    int2*     cand = (int2*)((char*)d_ws + ((size_t)1 << 20));
    _Float16* WT16 = (_Float16*)((char*)d_ws + ((size_t)40 << 20));
    _Float16* Ah   = (_Float16*)((char*)d_ws + ((size_t)64 << 20));
    _Float16* Bh   = (_Float16*)((char*)d_ws + ((size_t)96 << 20));

    k_prep<1><<<NBX + NBW + NBT + 1, 256, 0, stream>>>(x, b_pre, W_enc, W_dec,
                                                       Ah, Bh, WT16, cnt);
    k_encode_f16<1><<<(M / BM) * (DL / BN), 512, 0, stream>>>(Ah, Bh, b_enc, a,
                                                              cnt, cand, z);
    k_fast<<<M, 512, 0, stream>>>(cnt, cand, x, b_pre, W_enc, b_enc, kp, WT16, b_dec,
                                  z, xhat, flag);
    k_full<0, 0><<<M, 512, 0, stream>>>(a, x, b_pre, W_enc, b_enc, kp, WT16, b_dec,
                                        z, xhat, flag);
  } else {       // small-ws fallback: z-region scratch, full-row back end for all rows
    _Float16* WT16 = (_Float16*)z;
    _Float16* Ah   = (_Float16*)(z + (size_t)12 * 1024 * 1024);
    _Float16* Bh   = (_Float16*)(z + (size_t)20 * 1024 * 1024);

    k_prep<0><<<NBX + NBW + NBT, 256, 0, stream>>>(x, b_pre, W_enc, W_dec,
                                                   Ah, Bh, WT16, nullptr);
    k_encode_f16<0><<<(M / BM) * (DL / BN), 512, 0, stream>>>(Ah, Bh, b_enc, a,
                                                              nullptr, nullptr, nullptr);
    k_full<1, 1><<<M, 512, 0, stream>>>(a, x, b_pre, W_enc, b_enc, kp, WT16, b_dec,
                                        z, xhat, nullptr);
  }
}

// Round 13
// 629.552 us; speedup vs baseline: 1.1129x; 1.1129x over previous
//
#include <hip/hip_runtime.h>

#define DIN 768
#define DL  12288
#define CAP 320
#define CAP2 512
#define WCAP 256
#define TCAND 2.9f
#define MARGIN 0.03f
#define UB 0.015f
#define UMAX 64
#define KMAX 128

typedef __attribute__((ext_vector_type(8))) _Float16 half8;
typedef __attribute__((ext_vector_type(4))) _Float16 half4v;
typedef __attribute__((ext_vector_type(4))) float f32x4;

__device__ __forceinline__ void gl_lds16(const void* g, void* s) {
  __builtin_amdgcn_global_load_lds(
      (const __attribute__((address_space(1))) unsigned int*)g,
      (__attribute__((address_space(3))) unsigned int*)s, 16, 0, 0);
}
__device__ __forceinline__ void wait_lgkm0_fence() {
  asm volatile("s_waitcnt lgkmcnt(0)" ::: "memory");
  __builtin_amdgcn_sched_barrier(0);   // rule #18
}
__device__ __forceinline__ void wait_vm0() {
  asm volatile("s_waitcnt vmcnt(0)" ::: "memory");
}

// ------- merged prep: split_x | split_w | transpose | cnt/flag zero (block-range) -------
#define NBX (8192 * DIN / 1024)          // 6144
#define NBW (DL * DIN / 1024)            // 9216
#define NBT ((DL / 32) * (DIN / 32))     // 9216

template <int ZMETA>
__global__ __launch_bounds__(256) void k_prep(
    const float* __restrict__ x, const float* __restrict__ b_pre,
    const float* __restrict__ W_enc, const float* __restrict__ W_dec,
    _Float16* __restrict__ Ah, _Float16* __restrict__ Bh, _Float16* __restrict__ WT,
    int* __restrict__ meta)   // cnt(8192) + flag(8192)
{
  const int b = blockIdx.x, tid = threadIdx.x;
  if (b < NBX) {
    const int i4 = b * 256 + tid;
    const int col4 = (i4 % (DIN / 4)) * 4;
    const float4 xv = *(const float4*)&x[(size_t)i4 * 4];
    const float4 bp = *(const float4*)&b_pre[col4];
    half4v o;
    o.x = (_Float16)(xv.x - bp.x);
    o.y = (_Float16)(xv.y - bp.y);
    o.z = (_Float16)(xv.z - bp.z);
    o.w = (_Float16)(xv.w - bp.w);
    *(half4v*)&Ah[(size_t)i4 * 4] = o;
  } else if (b < NBX + NBW) {
    const int i4 = (b - NBX) * 256 + tid;
    const float4 wv = *(const float4*)&W_enc[(size_t)i4 * 4];
    half4v o;
    o.x = (_Float16)wv.x; o.y = (_Float16)wv.y;
    o.z = (_Float16)wv.z; o.w = (_Float16)wv.w;
    *(half4v*)&Bh[(size_t)i4 * 4] = o;
  } else if (b < NBX + NBW + NBT) {
    const int idx = b - NBX - NBW;
    const int c0 = (idx % (DL / 32)) * 32;
    const int r0 = (idx / (DL / 32)) * 32;
    const int xx = tid & 31, yy = tid >> 5;
    __shared__ float t[32][33];
#pragma unroll
    for (int dy = 0; dy < 32; dy += 8)
      t[yy + dy][xx] = W_dec[(size_t)(r0 + yy + dy) * DL + c0 + xx];
    __syncthreads();
#pragma unroll
    for (int dy = 0; dy < 32; dy += 8)
      WT[(size_t)(c0 + yy + dy) * DIN + r0 + xx] = (_Float16)t[xx][yy + dy];
  } else if (ZMETA) {
    const int4 z4 = {0, 0, 0, 0};   // 16384 ints = 4096 int4; 256 thr x 16
#pragma unroll
    for (int s = 0; s < 16; ++s) ((int4*)meta)[tid * 16 + s] = z4;
  }
}

// ------- fp16 MFMA encode: reuse-aware fragment loads (24 ds_read/tile, was 48) ---------
#define BM 256
#define BN 256
#define BKE 64
#define NKT (DIN / BKE)   // 12

template <int EMIT>
__global__ __launch_bounds__(512) void k_encode_f16(
    const _Float16* __restrict__ Ah, const _Float16* __restrict__ Bh,
    const float* __restrict__ b_enc, float* __restrict__ aout,
    int* __restrict__ cnt, int2* __restrict__ cand)
{
  __shared__ _Float16 sA[2][BM][BKE];
  __shared__ _Float16 sB[2][BN][BKE];
  __shared__ int s_bcnt8[8];
  __shared__ int s_ovf;
  const int tid = threadIdx.x, wave = tid >> 6, lane = tid & 63;
  const int wm = wave >> 2, wn = wave & 3;
  const int fr = lane & 15, fc = lane >> 4;

  const int q = ((8192 / BM) * (DL / BN)) >> 3;
  const int wg = (blockIdx.x & 7) * q + (blockIdx.x >> 3);
  const int bm = (wg / (DL / BN)) * BM;
  const int bn = (wg % (DL / BN)) * BN;

  const int lrow = lane >> 3;
  const int lcol = ((lane & 7) ^ lrow) << 3;
  const _Float16* gA = Ah + (size_t)(bm + lrow) * DIN + lcol;
  const _Float16* gB = Bh + (size_t)(bn + lrow) * DIN + lcol;

  f32x4 acc[8][4];
#pragma unroll
  for (int i = 0; i < 8; ++i)
#pragma unroll
    for (int j = 0; j < 4; ++j) acc[i][j] = f32x4{0.f, 0.f, 0.f, 0.f};

#define STAGE_TILE(buf, tt)                                                      \
  {                                                                              \
    _Pragma("unroll")                                                            \
    for (int s4 = 0; s4 < 4; ++s4) {                                             \
      const int s8 = (wave + s4 * 8) * 8;                                        \
      gl_lds16(gA + (size_t)s8 * DIN + (tt) * BKE, &sA[buf][s8][0]);             \
      gl_lds16(gB + (size_t)s8 * DIN + (tt) * BKE, &sB[buf][s8][0]);             \
    }                                                                            \
  }

  // A-fragments for half mh (8 x b128); B-fragments for half nh (4 x b128)
#define LOAD_AF(p, mh)                                                           \
  {                                                                              \
    const char* bA = (const char*)&sA[p][0][0];                                  \
    _Pragma("unroll")                                                            \
    for (int i = 0; i < 4; ++i)                                                  \
      _Pragma("unroll")                                                          \
      for (int ks = 0; ks < 2; ++ks) {                                           \
        const int row = wm * 128 + ((mh) * 4 + i) * 16 + fr;                     \
        const int ph = (ks * 4 + fc) ^ (fr & 7);                                 \
        af[i][ks] = *(const half8*)(bA + row * (BKE * 2) + ph * 16);             \
      }                                                                          \
  }
#define LOAD_BF(p, nh)                                                           \
  {                                                                              \
    const char* bB = (const char*)&sB[p][0][0];                                  \
    _Pragma("unroll")                                                            \
    for (int j = 0; j < 2; ++j)                                                  \
      _Pragma("unroll")                                                          \
      for (int ks = 0; ks < 2; ++ks) {                                           \
        const int row = wn * 64 + ((nh) * 2 + j) * 16 + fr;                      \
        const int ph = (ks * 4 + fc) ^ (fr & 7);                                 \
        bf[nh][j][ks] = *(const half8*)(bB + row * (BKE * 2) + ph * 16);         \
      }                                                                          \
  }

#define MFMAQ(mh, nh)                                                            \
  __builtin_amdgcn_s_setprio(1);                                                 \
  _Pragma("unroll")                                                              \
  for (int i = 0; i < 4; ++i)                                                    \
    _Pragma("unroll")                                                            \
    for (int j = 0; j < 2; ++j)                                                  \
      _Pragma("unroll")                                                          \
      for (int ks = 0; ks < 2; ++ks)                                             \
        acc[(mh) * 4 + i][(nh) * 2 + j] = __builtin_amdgcn_mfma_f32_16x16x32_f16( \
            af[i][ks], bf[nh][j][ks], acc[(mh) * 4 + i][(nh) * 2 + j], 0, 0, 0); \
  __builtin_amdgcn_s_setprio(0);

  half8 af[4][2], bf[2][2][2];

  STAGE_TILE(0, 0)
  wait_vm0();
  __builtin_amdgcn_s_barrier();

#pragma unroll 1
  for (int t = 0; t < NKT; ++t) {
    const int p = t & 1;
    // phase 0: af(0) + bf(0) + next-tile stage issue
    LOAD_AF(p, 0)
    LOAD_BF(p, 0)
    if (t + 1 < NKT) STAGE_TILE(p ^ 1, t + 1)
    __builtin_amdgcn_s_barrier();
    wait_lgkm0_fence();
    MFMAQ(0, 0)
    __builtin_amdgcn_s_barrier();
    // phase 1: bf(1) only (af kept in regs)
    LOAD_BF(p, 1)
    __builtin_amdgcn_s_barrier();
    wait_lgkm0_fence();
    MFMAQ(0, 1)
    __builtin_amdgcn_s_barrier();
    // phase 2: af(1) only (both bf kept); drain stage; then TWO MFMA quadrants, no loads
    LOAD_AF(p, 1)
    wait_vm0();
    __builtin_amdgcn_s_barrier();
    wait_lgkm0_fence();
    MFMAQ(1, 1)
    MFMAQ(1, 0)
    __builtin_amdgcn_s_barrier();
  }

  // K-loop LDS done; reuse sA/sB as candidate scratch
  unsigned* pk   = (unsigned*)&sA[0][0][0];   // 8 segments x WCAP packed (lrow<<8|lcol)
  float*    pv   = (float*)&sA[1][0][0];
  int*      lcnt = (int*)&sB[0][0][0];        // 256 per-local-row counts -> cursors
  if (EMIT) {
    if (tid < 8) s_bcnt8[tid] = 0;
    if (tid == 0) s_ovf = 0;
    if (tid < 256) lcnt[tid] = 0;
    __syncthreads();
  }

#pragma unroll
  for (int j = 0; j < 4; ++j) {
    const int col = bn + wn * 64 + j * 16 + fr;
    const float be = b_enc[col];
#pragma unroll
    for (int i = 0; i < 8; ++i) {
      const int row0 = bm + wm * 128 + i * 16 + fc * 4;
#pragma unroll
      for (int r = 0; r < 4; ++r) {
        const float v = acc[i][j][r] + be;
        aout[(size_t)(row0 + r) * DL + col] = v;
        if (EMIT && v > TCAND) {           // LDS-only, per-wave-sharded counters
          const int lr = wm * 128 + i * 16 + fc * 4 + r;
          const int lc = wn * 64 + j * 16 + fr;
          const int p2 = atomicAdd(&s_bcnt8[wave], 1);
          if (p2 < WCAP) {
            pk[wave * WCAP + p2] = ((unsigned)lr << 8) | (unsigned)lc;
            pv[wave * WCAP + p2] = v;
          }
          atomicAdd(&lcnt[lr], 1);
        }
      }
    }
  }

  if (EMIT) {
    __syncthreads();
    if (tid < 8 && s_bcnt8[tid] > WCAP) s_ovf = 1;
    __syncthreads();
    if (s_ovf) {
      // overflow (P~0): poison rows -> k_fast flags -> k_full redoes them
      if (tid < 256) atomicAdd(&cnt[bm + tid], CAP2);
    } else {
      if (tid < 256) {                     // one global reservation per row per block
        const int c = lcnt[tid];
        lcnt[tid] = c ? atomicAdd(&cnt[bm + tid], c) : 0;
      }
      __syncthreads();
#pragma unroll 1
      for (int w = 0; w < 8; ++w) {
        const int tw = s_bcnt8[w];
        for (int e = tid; e < tw; e += 512) {
          const unsigned pkv = pk[w * WCAP + e];
          const int lr = pkv >> 8, lc = pkv & 255u;
          const int p2 = atomicAdd(&lcnt[lr], 1);
          if (p2 < CAP2) {
            int2 o; o.x = __float_as_int(pv[w * WCAP + e]); o.y = bn + lc;
            cand[(size_t)(bm + lr) * CAP2 + p2] = o;
          }
        }
      }
    }
  }
#undef STAGE_TILE
#undef LOAD_AF
#undef LOAD_BF
#undef MFMAQ
}

// ====== FAST back end: candidates from encode; z zero+scatter; decode; flags deficits =====
__global__ __launch_bounds__(512) void k_fast(
    const int* __restrict__ cnt, const int2* __restrict__ cand,
    const float* __restrict__ x, const float* __restrict__ b_pre,
    const float* __restrict__ W, const float* __restrict__ b_enc,
    const int* __restrict__ kp, const _Float16* __restrict__ WT,
    const float* __restrict__ b_dec, float* __restrict__ z,
    float* __restrict__ xhat, int* __restrict__ flag)
{
  const int row = blockIdx.x, tid = threadIdx.x;
  const int wave = tid >> 6, lane = tid & 63;
  const int kk = min(max(kp[0], 1), KMAX);
  float* zr = z + (size_t)row * DL;

  __shared__ float cv[CAP2];
  __shared__ int ci[CAP2];
  __shared__ double x0[DIN];
  __shared__ float s_ak;
  __shared__ int s_nw, s_ucnt;
  __shared__ int uidx[UMAX];
  __shared__ double uex[UMAX];
  __shared__ int widx[KMAX];
  __shared__ float wval[KMAX];

  // z-zero (streams out while the block ranks candidates)
  const float4 zz = {0.f, 0.f, 0.f, 0.f};
#pragma unroll
  for (int j = 0; j < 6; ++j) ((float4*)zr)[tid + 512 * j] = zz;

  const int Craw = cnt[row];
  const int C = min(Craw, CAP2);
  for (int i = tid; i < C; i += 512) {
    const int2 p = cand[(size_t)row * CAP2 + i];
    cv[i] = __int_as_float(p.x);
    ci[i] = p.y;
  }
  for (int i = tid; i < DIN; i += 512)
    x0[i] = (double)x[(size_t)row * DIN + i] - (double)b_pre[i];
  if (tid == 0) { s_ak = -1e30f; s_nw = 0; s_ucnt = 0; }
  __syncthreads();

  bool defic = (Craw >= CAP2) || (C < kk);   // uniform
  if (!defic) {
    if (tid < C) {
      const float mv = cv[tid];
      const int mi = ci[tid];
      int r = 0;
      for (int j = 0; j < C; ++j) {
        const float fj = cv[j];
        if (fj > mv || (fj == mv && ci[j] < mi)) ++r;
      }
      if (r == kk - 1) s_ak = mv;
    }
    __syncthreads();
    if (s_ak - UB <= TCAND) defic = true;    // excluded (<=TCAND) values could reach band
  } else {
    __syncthreads();
  }
  if (defic) {
    if (tid == 0) flag[row] = 1;
    return;
  }
  const float ak = s_ak;

  if (tid < C) {
    const float mv = cv[tid];
    if (mv > ak + UB) {
      const int p = atomicAdd(&s_nw, 1);
      widx[p] = ci[tid]; wval[p] = mv;
    } else if (mv >= ak - UB) {
      const int p = atomicAdd(&s_ucnt, 1);
      if (p < UMAX) uidx[p] = ci[tid];
    }
  }
  __syncthreads();
  const int nci = s_nw;
  const int ucnt = min(s_ucnt, UMAX);

  for (int c = wave; c < ucnt; c += 8) {
    const int idx = uidx[c];
    const float* wrow = W + (size_t)idx * DIN;
    double s = 0.0;
#pragma unroll
    for (int it = 0; it < DIN / 64; ++it)
      s = fma(x0[lane + it * 64], (double)wrow[lane + it * 64], s);
#pragma unroll
    for (int mm = 32; mm; mm >>= 1) s += __shfl_xor(s, mm);
    if (lane == 0) {
      const double e = s + (double)b_enc[idx];
      uex[c] = e > 0.0 ? e : 0.0;
    }
  }
  __syncthreads();

  const int utake = min(kk - nci, ucnt);
  if (tid < ucnt) {
    const double mv = uex[tid];
    const int mi = uidx[tid];
    int r = 0;
    for (int j = 0; j < ucnt; ++j) {
      const double fj = uex[j];
      if (fj > mv || (fj == mv && uidx[j] < mi)) ++r;
    }
    if (r < utake) {
      const int p = atomicAdd(&s_nw, 1);
      widx[p] = mi; wval[p] = (float)mv;
    }
  }
  __syncthreads();
  const int nW = s_nw;

  if (tid < nW) zr[widx[tid]] = wval[tid];

  if (tid < 192) {
    float4 acc = ((const float4*)b_dec)[tid];
    for (int j = 0; j < nW; ++j) {
      const float vv = wval[j];
      const half4v w4 = *(const half4v*)(WT + (size_t)widx[j] * DIN + tid * 4);
      acc.x = fmaf(vv, (float)w4.x, acc.x);
      acc.y = fmaf(vv, (float)w4.y, acc.y);
      acc.z = fmaf(vv, (float)w4.z, acc.z);
      acc.w = fmaf(vv, (float)w4.w, acc.w);
    }
    ((float4*)(xhat + (size_t)row * DIN))[tid] = acc;
  }
}

// ====== FULL row back end (fallback for flagged rows; FORCE_ALL=1 for small-ws path) ======
template <int FORCE_ALL, int ZERO_Z>
__global__ __launch_bounds__(512) void k_full(
    const float* __restrict__ a, const float* __restrict__ x,
    const float* __restrict__ b_pre, const float* __restrict__ W,
    const float* __restrict__ b_enc, const int* __restrict__ kp,
    const _Float16* __restrict__ WT, const float* __restrict__ b_dec,
    float* __restrict__ z, float* __restrict__ xhat, const int* __restrict__ flag)
{
  const int row = blockIdx.x, tid = threadIdx.x;
  if (!FORCE_ALL && flag[row] == 0) return;
  const int wave = tid >> 6, lane = tid & 63;
  const int kk = min(max(kp[0], 1), KMAX);
  const float* ar = a + (size_t)row * DL;
  float* zr = z + (size_t)row * DL;

  __shared__ unsigned hist[4][512];
  __shared__ float s_wmax[8];
  __shared__ unsigned s_wsuf[8];
  __shared__ float s_Tm;
  __shared__ int s_cnt;
  __shared__ int cidx[CAP];
  __shared__ float caf[CAP];
  __shared__ double x0[DIN];
  __shared__ float s_ak;
  __shared__ int s_ucnt, s_nw;
  __shared__ int uidx[UMAX];
  __shared__ double uex[UMAX];
  __shared__ int widx[KMAX];
  __shared__ float wval[KMAX];

  float4 v[6];
#pragma unroll
  for (int j = 0; j < 6; ++j) {
    float4 t4 = ((const float4*)ar)[tid + 512 * j];
    t4.x = fmaxf(t4.x, 0.f); t4.y = fmaxf(t4.y, 0.f);
    t4.z = fmaxf(t4.z, 0.f); t4.w = fmaxf(t4.w, 0.f);
    v[j] = t4;
    if (ZERO_Z) {
      const float4 zz = {0.f, 0.f, 0.f, 0.f};
      ((float4*)zr)[tid + 512 * j] = zz;
    }
  }
  for (int i = tid; i < DIN; i += 512)
    x0[i] = (double)x[(size_t)row * DIN + i] - (double)b_pre[i];
  float m = 0.f;
#pragma unroll
  for (int j = 0; j < 6; ++j)
    m = fmaxf(m, fmaxf(fmaxf(v[j].x, v[j].y), fmaxf(v[j].z, v[j].w)));
#pragma unroll
  for (int off = 32; off; off >>= 1) m = fmaxf(m, __shfl_xor(m, off));
  if (lane == 0) s_wmax[wave] = m;
  if (tid == 0) { s_cnt = 0; s_Tm = -1.f; s_ak = -1e30f; s_ucnt = 0; s_nw = 0; }
  __syncthreads();
  float rmax = s_wmax[0];
#pragma unroll
  for (int w2 = 1; w2 < 8; ++w2) rmax = fmaxf(rmax, s_wmax[w2]);

  float Tm;
  if (rmax <= 0.f) {
    Tm = 1e30f;
  } else {
    const float scale = 512.f / rmax;
    unsigned need = (unsigned)kk;
    bool found = false;
    for (int phase = 0; phase < 2 && !found; ++phase) {
      for (int i = tid; i < 4 * 512; i += 512) (&hist[0][0])[i] = 0u;
      __syncthreads();
      unsigned* h = hist[wave & 3];
      const float sc = (phase == 0) ? scale : scale * 8.f;
#pragma unroll
      for (int j = 0; j < 6; ++j) {
        const float vv[4] = {v[j].x, v[j].y, v[j].z, v[j].w};
#pragma unroll
        for (int e = 0; e < 4; ++e) {
          const float val = vv[e];
          if (val > 0.f) {
            const float fb = val * scale;
            if (phase == 0) {
              if (fb >= 64.f) atomicAdd(&h[min(511, (int)fb)], 1u);
            } else {
              if (fb < 64.f) atomicAdd(&h[min(511, (int)(val * sc))], 1u);
            }
          }
        }
      }
      __syncthreads();
      const unsigned st = hist[0][tid] + hist[1][tid] + hist[2][tid] + hist[3][tid];
      unsigned s = st;
#pragma unroll
      for (int off = 1; off < 64; off <<= 1) {
        const unsigned o = __shfl_down(s, off);
        if (lane + off < 64) s += o;
      }
      if (lane == 0) s_wsuf[wave] = s;
      __syncthreads();
      unsigned above_w = 0, total = 0;
#pragma unroll
      for (int w2 = 0; w2 < 8; ++w2) {
        total += s_wsuf[w2];
        if (w2 > wave) above_w += s_wsuf[w2];
      }
      const unsigned inc = s + above_w;
      const unsigned excl = inc - st;
      if (total >= need) {
        if (inc >= need && excl < need)
          s_Tm = (float)tid / sc - MARGIN;
        found = true;
      } else {
        need -= total;
      }
      __syncthreads();
    }
    Tm = s_Tm;
  }

#pragma unroll
  for (int j = 0; j < 6; ++j) {
    const float vv[4] = {v[j].x, v[j].y, v[j].z, v[j].w};
#pragma unroll
    for (int e = 0; e < 4; ++e) {
      if (vv[e] > 0.f && vv[e] >= Tm) {
        const int p = atomicAdd(&s_cnt, 1);
        if (p < CAP) { cidx[p] = (tid + 512 * j) * 4 + e; caf[p] = vv[e]; }
      }
    }
  }
  __syncthreads();
  const int C = min(s_cnt, CAP);

  if (C > kk) {
    if (tid < C) {
      const float mv = caf[tid];
      const int mi = cidx[tid];
      int r = 0;
      for (int j = 0; j < C; ++j) {
        const float fj = caf[j];
        if (fj > mv || (fj == mv && cidx[j] < mi)) ++r;
      }
      if (r == kk - 1) s_ak = mv;
    }
    __syncthreads();
  }
  const float ak = s_ak;

  if (tid < C) {
    const float mv = caf[tid];
    if (C <= kk || mv > ak + UB) {
      const int p = atomicAdd(&s_nw, 1);
      widx[p] = cidx[tid]; wval[p] = mv;
    } else if (mv >= ak - UB) {
      const int p = atomicAdd(&s_ucnt, 1);
      if (p < UMAX) uidx[p] = cidx[tid];
    }
  }
  __syncthreads();
  const int nci = s_nw;
  const int ucnt = min(s_ucnt, UMAX);

  for (int c = wave; c < ucnt; c += 8) {
    const int idx = uidx[c];
    const float* wrow = W + (size_t)idx * DIN;
    double s = 0.0;
#pragma unroll
    for (int it = 0; it < DIN / 64; ++it)
      s = fma(x0[lane + it * 64], (double)wrow[lane + it * 64], s);
#pragma unroll
    for (int mm = 32; mm; mm >>= 1) s += __shfl_xor(s, mm);
    if (lane == 0) {
      const double e = s + (double)b_enc[idx];
      uex[c] = e > 0.0 ? e : 0.0;
    }
  }
  __syncthreads();

  const int utake = min(kk - nci, ucnt);
  if (tid < ucnt) {
    const double mv = uex[tid];
    const int mi = uidx[tid];
    int r = 0;
    for (int j = 0; j < ucnt; ++j) {
      const double fj = uex[j];
      if (fj > mv || (fj == mv && uidx[j] < mi)) ++r;
    }
    if (r < utake) {
      const int p = atomicAdd(&s_nw, 1);
      widx[p] = mi; wval[p] = (float)mv;
    }
  }
  __syncthreads();
  const int nW = s_nw;

  if (tid < nW) zr[widx[tid]] = wval[tid];

  if (tid < 192) {
    float4 acc = ((const float4*)b_dec)[tid];
    for (int j = 0; j < nW; ++j) {
      const float vv = wval[j];
      const half4v w4 = *(const half4v*)(WT + (size_t)widx[j] * DIN + tid * 4);
      acc.x = fmaf(vv, (float)w4.x, acc.x);
      acc.y = fmaf(vv, (float)w4.y, acc.y);
      acc.z = fmaf(vv, (float)w4.z, acc.z);
      acc.w = fmaf(vv, (float)w4.w, acc.w);
    }
    ((float4*)(xhat + (size_t)row * DIN))[tid] = acc;
  }
}

extern "C" void kernel_launch(void* const* d_in, const int* in_sizes, int n_in,
                              void* d_out, int out_size, void* d_ws, size_t ws_size,
                              hipStream_t stream)
{
  const float* x     = (const float*)d_in[0];
  const float* b_pre = (const float*)d_in[1];
  const float* W_enc = (const float*)d_in[2];
  const float* b_enc = (const float*)d_in[3];
  const float* W_dec = (const float*)d_in[4];
  const float* b_dec = (const float*)d_in[5];
  const int*   kp    = (const int*)d_in[6];
  const int M = in_sizes[0] / DIN;   // 8192

  float* xhat = (float*)d_out;
  float* z    = xhat + (size_t)M * DIN;
  float* a    = z + (size_t)M * DL;

  const bool bigws = ws_size >= ((size_t)192 << 20);

  if (bigws) {   // d_ws: [0,64K) cnt+flag | [1M,34.6M) cand | [40M) WT16 | [64M) Ah | [96M) Bh
    int*      cnt  = (int*)d_ws;
    int*      flag = (int*)d_ws + M;
    int2*     cand = (int2*)((char*)d_ws + ((size_t)1 << 20));
    _Float16* WT16 = (_Float16*)((char*)d_ws + ((size_t)40 << 20));
    _Float16* Ah   = (_Float16*)((char*)d_ws + ((size_t)64 << 20));
    _Float16* Bh   = (_Float16*)((char*)d_ws + ((size_t)96 << 20));

    k_prep<1><<<NBX + NBW + NBT + 1, 256, 0, stream>>>(x, b_pre, W_enc, W_dec,
                                                       Ah, Bh, WT16, cnt);
    k_encode_f16<1><<<(M / BM) * (DL / BN), 512, 0, stream>>>(Ah, Bh, b_enc, a,
                                                              cnt, cand);
    k_fast<<<M, 512, 0, stream>>>(cnt, cand, x, b_pre, W_enc, b_enc, kp, WT16, b_dec,
                                  z, xhat, flag);
    k_full<0, 0><<<M, 512, 0, stream>>>(a, x, b_pre, W_enc, b_enc, kp, WT16, b_dec,
                                        z, xhat, flag);
  } else {       // small-ws fallback: z-region scratch, full-row back end for all rows
    _Float16* WT16 = (_Float16*)z;
    _Float16* Ah   = (_Float16*)(z + (size_t)12 * 1024 * 1024);
    _Float16* Bh   = (_Float16*)(z + (size_t)20 * 1024 * 1024);

    k_prep<0><<<NBX + NBW + NBT, 256, 0, stream>>>(x, b_pre, W_enc, W_dec,
                                                   Ah, Bh, WT16, nullptr);
    k_encode_f16<0><<<(M / BM) * (DL / BN), 512, 0, stream>>>(Ah, Bh, b_enc, a,
                                                              nullptr, nullptr);
    k_full<1, 1><<<M, 512, 0, stream>>>(a, x, b_pre, W_enc, b_enc, kp, WT16, b_dec,
                                        z, xhat, nullptr);
  }
}